// Round 13
// baseline (158.064 us; speedup 1.0000x reference)
//
#include <hip/hip_runtime.h>
#include <math.h>

// MS-SSIM, 5 levels, fp32, N=32 of 512x512.
// R13: R12 base + XOR column swizzle in the hb LDS buffer:
//      column c stored at c ^ ((c>>2)&3). Stage-A v4f writes (64B lane
//      stride, was 4-way bank conflict = 4.2M cycles) become 2-way (free);
//      stage-B reads remain conflict-free. ~4 extra v_xor per stage-A item.
//      Carried: 4-channel sum/diff blur, v4f LDS, fast rcp, packed epilogue,
//      folded constants, interior fast path, lb(256,7), d1 = pyramid + L0,
//      d2 = L1-4, tiny finalize, unique result slots.

typedef float v2f __attribute__((ext_vector_type(2)));
typedef float v4f __attribute__((ext_vector_type(4)));

#define TILE 32
#define HALO 5
#define SROWS 42   // TILE + 2*HALO
#define SMEM_FLOATS 5384  // hb v4f[SROWS*TILE] = 5376f | red 8f

struct GaussW { float w[11]; };

#define C1X2 (2.0f * 0.01f * 0.01f)
#define C2X2 (2.0f * 0.03f * 0.03f)

__device__ __forceinline__ void ssim_tile(
        const float* __restrict__ p1, const float* __restrict__ p2,
        int W, int tile_x, int tile_y, const GaussW& gw,
        float2* __restrict__ resslot, float* smem, int tid) {
    v4f* hb = (v4f*)smem;                 // [SROWS*TILE] {bs,bd,bs2,bd2}
    float* red = smem + 4 * SROWS * TILE; // [8]

    const bool xfast = (tile_x >= 8) && (tile_x + TILE + 8 <= W);
    const bool allfast = xfast && (tile_y > 0) && (tile_y + TILE < W);

    // ---- stage A: horizontal blur of (s,d) and (s^2,d^2) ----
    for (int it = tid; it < SROWS * 8; it += 256) {
        int r = it >> 3, c4 = it & 7;
        int gy = tile_y + r - HALO;
        int gx0 = tile_x + (c4 << 2) - 8;
        const float* row1 = p1 + (size_t)gy * W;
        const float* row2 = p2 + (size_t)gy * W;
        float a1[20], a2[20];
        if (allfast) {
#pragma unroll
            for (int q = 0; q < 5; q++) {
                float4 v1 = *(const float4*)(row1 + gx0 + q * 4);
                float4 v2v = *(const float4*)(row2 + gx0 + q * 4);
                a1[q*4+0] = v1.x;  a1[q*4+1] = v1.y;  a1[q*4+2] = v1.z;  a1[q*4+3] = v1.w;
                a2[q*4+0] = v2v.x; a2[q*4+1] = v2v.y; a2[q*4+2] = v2v.z; a2[q*4+3] = v2v.w;
            }
        } else {
            bool rowok = (gy >= 0) && (gy < W);
#pragma unroll
            for (int i = 0; i < 20; i++) { a1[i] = 0.f; a2[i] = 0.f; }
            if (xfast) {
                if (rowok) {
#pragma unroll
                    for (int q = 0; q < 5; q++) {
                        float4 v1 = *(const float4*)(row1 + gx0 + q * 4);
                        float4 v2v = *(const float4*)(row2 + gx0 + q * 4);
                        a1[q*4+0] = v1.x;  a1[q*4+1] = v1.y;  a1[q*4+2] = v1.z;  a1[q*4+3] = v1.w;
                        a2[q*4+0] = v2v.x; a2[q*4+1] = v2v.y; a2[q*4+2] = v2v.z; a2[q*4+3] = v2v.w;
                    }
                }
            } else {
#pragma unroll
                for (int q = 0; q < 5; q++) {
                    int g = gx0 + q * 4;
                    if (rowok && g >= 0 && g + 4 <= W) {
                        float4 v1 = *(const float4*)(row1 + g);
                        float4 v2v = *(const float4*)(row2 + g);
                        a1[q*4+0] = v1.x;  a1[q*4+1] = v1.y;  a1[q*4+2] = v1.z;  a1[q*4+3] = v1.w;
                        a2[q*4+0] = v2v.x; a2[q*4+1] = v2v.y; a2[q*4+2] = v2v.z; a2[q*4+3] = v2v.w;
                    }
                }
            }
        }
        v2f SD[14], SQ[14];
#pragma unroll
        for (int i = 0; i < 14; i++) {
            float x = a1[i + 3], y = a2[i + 3];
            v2f sd = {x + y, x - y};
            SD[i] = sd;
            SQ[i] = sd * sd;
        }
        v2f hsd[4] = {(v2f)(0.f), (v2f)(0.f), (v2f)(0.f), (v2f)(0.f)};
        v2f hsq[4] = {(v2f)(0.f), (v2f)(0.f), (v2f)(0.f), (v2f)(0.f)};
#pragma unroll
        for (int k = 0; k < 11; k++) {
            float wk = gw.w[k];
#pragma unroll
            for (int j = 0; j < 4; j++) {
                hsd[j] += wk * SD[j + k];
                hsq[j] += wk * SQ[j + k];
            }
        }
        // swizzled store: column (4*c4+j) -> index 4*c4 + (j ^ (c4&3))
        int obase = r * TILE + (c4 << 2);
        int c4m3 = c4 & 3;
#pragma unroll
        for (int j = 0; j < 4; j++) {
            hb[obase + (j ^ c4m3)] = (v4f){hsd[j].x, hsd[j].y, hsq[j].x, hsq[j].y};
        }
    }
    __syncthreads();

    // ---- stage B: vertical blur (b128 reads, swizzled col) + ssim/mcs ----
    float ssim_v = 0.f, mcs_v = 0.f;
    {
        int tx = tid & 31, y0 = (tid >> 5) * 4;
        int txs = tx ^ ((tx >> 2) & 3);   // swizzled column index
        v4f m[4];
        {
            v4f v[14];
#pragma unroll
            for (int r = 0; r < 14; r++) v[r] = hb[(y0 + r) * TILE + txs];
#pragma unroll
            for (int j = 0; j < 4; j++) {
                v4f s = (v4f)(0.f);
#pragma unroll
                for (int k = 0; k < 11; k++) s += gw.w[k] * v[j + k];
                m[j] = s;
            }
        }
#pragma unroll
        for (int p = 0; p < 2; p++) {
            v2f bs  = {m[2*p].x, m[2*p+1].x};
            v2f bd  = {m[2*p].y, m[2*p+1].y};
            v2f bs2 = {m[2*p].z, m[2*p+1].z};
            v2f bd2 = {m[2*p].w, m[2*p+1].w};
            v2f qp = bs * bs, qm = bd * bd;
            v2f u = bs2 - qp, v = bd2 - qm;
            v2f mden = (u + v) + (v2f)(C2X2);
            v2f sden = (qp + qm) + (v2f)(C1X2);
            v2f rm = {__builtin_amdgcn_rcpf(mden.x), __builtin_amdgcn_rcpf(mden.y)};
            v2f rs = {__builtin_amdgcn_rcpf(sden.x), __builtin_amdgcn_rcpf(sden.y)};
            v2f mcs  = ((u - v) + (v2f)(C2X2)) * rm;
            v2f ssim = ((qp - qm) + (v2f)(C1X2)) * rs * mcs;
            ssim_v += ssim.x + ssim.y;
            mcs_v  += mcs.x + mcs.y;
        }
    }

    // ---- block reduction + unique-slot store ----
#pragma unroll
    for (int off = 32; off > 0; off >>= 1) {
        ssim_v += __shfl_down(ssim_v, off);
        mcs_v  += __shfl_down(mcs_v, off);
    }
    int wave = tid >> 6, lane = tid & 63;
    if (lane == 0) { red[wave] = ssim_v; red[4 + wave] = mcs_v; }
    __syncthreads();
    if (tid == 0) {
        float S = red[0] + red[1] + red[2] + red[3];
        float M = red[4] + red[5] + red[6] + red[7];
        *resslot = make_float2(S, M);
    }
}

// pyramid region: 64x64 of L0 -> L1 32x32 (store), L2 16x16, L3 8x8, L4 4x4
__device__ __forceinline__ void pyramid_region(
        const float* __restrict__ in1, const float* __restrict__ in2,
        int n, int reg,
        float* __restrict__ l1a, float* __restrict__ l1b,
        float* __restrict__ l2a, float* __restrict__ l2b,
        float* __restrict__ l3a, float* __restrict__ l3b,
        float* __restrict__ l4a, float* __restrict__ l4b,
        float* smem, int tid) {
    float* b1 = smem;          // 32*32 (L1)
    float* b2 = smem + 1024;
    float* c1 = smem + 2048;   // 16*16 (L2)
    float* c2 = smem + 2304;
    float* d1 = smem + 2560;   // 8*8 (L3)
    float* d2 = smem + 2624;
    const int rx = reg & 7, ry = reg >> 3;
    const float* p1 = in1 + (size_t)n * 512 * 512;
    const float* p2 = in2 + (size_t)n * 512 * 512;

    // L1 (store)
    for (int i = tid; i < 32 * 16; i += 256) {
        int oy = i >> 4, oxp = i & 15;
        int gy = ry * 64 + 2 * oy, gx = rx * 64 + 4 * oxp;
        float4 r10 = *(const float4*)(p1 + (size_t)gy * 512 + gx);
        float4 r11 = *(const float4*)(p1 + (size_t)(gy + 1) * 512 + gx);
        float4 r20 = *(const float4*)(p2 + (size_t)gy * 512 + gx);
        float4 r21 = *(const float4*)(p2 + (size_t)(gy + 1) * 512 + gx);
        float2 o1 = make_float2(0.25f * (r10.x + r10.y + r11.x + r11.y),
                                0.25f * (r10.z + r10.w + r11.z + r11.w));
        float2 o2 = make_float2(0.25f * (r20.x + r20.y + r21.x + r21.y),
                                0.25f * (r20.z + r20.w + r21.z + r21.w));
        *(float2*)&b1[oy * 32 + 2 * oxp] = o1;
        *(float2*)&b2[oy * 32 + 2 * oxp] = o2;
        size_t o = (size_t)n * 256 * 256 + (size_t)(ry * 32 + oy) * 256 + rx * 32 + 2 * oxp;
        *(float2*)&l1a[o] = o1;
        *(float2*)&l1b[o] = o2;
    }
    __syncthreads();
    // L2 (store)
    if (tid < 16 * 8) {
        int oy = tid >> 3, oxp = tid & 7;
        float4 r10 = *(const float4*)&b1[(2 * oy) * 32 + 4 * oxp];
        float4 r11 = *(const float4*)&b1[(2 * oy + 1) * 32 + 4 * oxp];
        float4 r20 = *(const float4*)&b2[(2 * oy) * 32 + 4 * oxp];
        float4 r21 = *(const float4*)&b2[(2 * oy + 1) * 32 + 4 * oxp];
        float2 o1 = make_float2(0.25f * (r10.x + r10.y + r11.x + r11.y),
                                0.25f * (r10.z + r10.w + r11.z + r11.w));
        float2 o2 = make_float2(0.25f * (r20.x + r20.y + r21.x + r21.y),
                                0.25f * (r20.z + r20.w + r21.z + r21.w));
        *(float2*)&c1[oy * 16 + 2 * oxp] = o1;
        *(float2*)&c2[oy * 16 + 2 * oxp] = o2;
        size_t o = (size_t)n * 128 * 128 + (size_t)(ry * 16 + oy) * 128 + rx * 16 + 2 * oxp;
        *(float2*)&l2a[o] = o1;
        *(float2*)&l2b[o] = o2;
    }
    __syncthreads();
    // L3 (store)
    if (tid < 8 * 4) {
        int oy = tid >> 2, oxp = tid & 3;
        float4 r10 = *(const float4*)&c1[(2 * oy) * 16 + 4 * oxp];
        float4 r11 = *(const float4*)&c1[(2 * oy + 1) * 16 + 4 * oxp];
        float4 r20 = *(const float4*)&c2[(2 * oy) * 16 + 4 * oxp];
        float4 r21 = *(const float4*)&c2[(2 * oy + 1) * 16 + 4 * oxp];
        float2 o1 = make_float2(0.25f * (r10.x + r10.y + r11.x + r11.y),
                                0.25f * (r10.z + r10.w + r11.z + r11.w));
        float2 o2 = make_float2(0.25f * (r20.x + r20.y + r21.x + r21.y),
                                0.25f * (r20.z + r20.w + r21.z + r21.w));
        *(float2*)&d1[oy * 8 + 2 * oxp] = o1;
        *(float2*)&d2[oy * 8 + 2 * oxp] = o2;
        size_t o = (size_t)n * 64 * 64 + (size_t)(ry * 8 + oy) * 64 + rx * 8 + 2 * oxp;
        *(float2*)&l3a[o] = o1;
        *(float2*)&l3b[o] = o2;
    }
    __syncthreads();
    // L4 (store)
    if (tid < 4 * 2) {
        int oy = tid >> 1, oxp = tid & 1;
        float4 r10 = *(const float4*)&d1[(2 * oy) * 8 + 4 * oxp];
        float4 r11 = *(const float4*)&d1[(2 * oy + 1) * 8 + 4 * oxp];
        float4 r20 = *(const float4*)&d2[(2 * oy) * 8 + 4 * oxp];
        float4 r21 = *(const float4*)&d2[(2 * oy + 1) * 8 + 4 * oxp];
        float2 o1 = make_float2(0.25f * (r10.x + r10.y + r11.x + r11.y),
                                0.25f * (r10.z + r10.w + r11.z + r11.w));
        float2 o2 = make_float2(0.25f * (r20.x + r20.y + r21.x + r21.y),
                                0.25f * (r20.z + r20.w + r21.z + r21.w));
        size_t o = (size_t)n * 32 * 32 + (size_t)(ry * 4 + oy) * 32 + rx * 4 + 2 * oxp;
        *(float2*)&l4a[o] = o1;
        *(float2*)&l4b[o] = o2;
    }
}

// D1: t<64 pyramid region; t in [64,320) L0 tile.
__global__ __launch_bounds__(256, 7) void d1_kernel(
        const float* __restrict__ i0a, const float* __restrict__ i0b,
        float* __restrict__ l1a, float* __restrict__ l1b,
        float* __restrict__ l2a, float* __restrict__ l2b,
        float* __restrict__ l3a, float* __restrict__ l3b,
        float* __restrict__ l4a, float* __restrict__ l4b,
        float2* __restrict__ res0, GaussW gw) {
    __shared__ float smem[SMEM_FLOATS];
    const int tid = threadIdx.x;
    const int t = blockIdx.x;
    const int n = blockIdx.y;
    if (t < 64) {
        pyramid_region(i0a, i0b, n, t, l1a, l1b, l2a, l2b, l3a, l3b, l4a, l4b,
                       smem, tid);
    } else {
        int idx = t - 64;
        const float* p1 = i0a + (size_t)n * 512 * 512;
        const float* p2 = i0b + (size_t)n * 512 * 512;
        ssim_tile(p1, p2, 512, (idx & 15) << 5, (idx >> 4) << 5,
                  gw, &res0[n * 256 + idx], smem, tid);
    }
}

// D2: t<64 L1 tile; [64,80) L2; [80,84) L3; 84 L4.
__global__ __launch_bounds__(256, 7) void d2_kernel(
        const float* __restrict__ l1a, const float* __restrict__ l1b,
        const float* __restrict__ l2a, const float* __restrict__ l2b,
        const float* __restrict__ l3a, const float* __restrict__ l3b,
        const float* __restrict__ l4a, const float* __restrict__ l4b,
        float2* __restrict__ res1, float2* __restrict__ res2,
        float2* __restrict__ res3, float2* __restrict__ res4, GaussW gw) {
    __shared__ float smem[SMEM_FLOATS];
    const int tid = threadIdx.x;
    const int t = blockIdx.x;
    const int n = blockIdx.y;
    const float* b1;
    const float* b2;
    int W, tx, ty;
    float2* slot;
    if (t < 64)      { W = 256; b1 = l1a; b2 = l1b; tx = (t & 7) << 5; ty = (t >> 3) << 5; slot = &res1[n * 64 + t]; }
    else if (t < 80) { int i = t - 64; W = 128; b1 = l2a; b2 = l2b; tx = (i & 3) << 5; ty = (i >> 2) << 5; slot = &res2[n * 16 + i]; }
    else if (t < 84) { int i = t - 80; W = 64; b1 = l3a; b2 = l3b; tx = (i & 1) << 5; ty = (i >> 1) << 5; slot = &res3[n * 4 + i]; }
    else             { W = 32; b1 = l4a; b2 = l4b; tx = 0; ty = 0; slot = &res4[n]; }
    ssim_tile(b1 + (size_t)n * W * W, b2 + (size_t)n * W * W, W,
              tx, ty, gw, slot, smem, tid);
}

__global__ void finalize_kernel(const float2* __restrict__ res0,
                                const float2* __restrict__ res1,
                                const float2* __restrict__ res2,
                                const float2* __restrict__ res3,
                                const float2* __restrict__ res4,
                                float* __restrict__ out, int N) {
    __shared__ float2 redf[5][4];
    const int tid = threadIdx.x;
    const float2* rr[5] = {res0, res1, res2, res3, res4};
    const int cnts[5] = {N * 256, N * 64, N * 16, N * 4, N};
#pragma unroll
    for (int l = 0; l < 5; l++) {
        float sx = 0.f, sy = 0.f;
        for (int i = tid; i < cnts[l]; i += 256) {
            float2 v = rr[l][i];
            sx += v.x;
            sy += v.y;
        }
#pragma unroll
        for (int off = 32; off > 0; off >>= 1) {
            sx += __shfl_down(sx, off);
            sy += __shfl_down(sy, off);
        }
        if ((tid & 63) == 0) redf[l][tid >> 6] = make_float2(sx, sy);
    }
    __syncthreads();
    if (tid == 0) {
        const float wts[5] = {0.0448f, 0.2856f, 0.3001f, 0.2363f, 0.1333f};
        float r = 1.f;
#pragma unroll
        for (int l = 0; l < 5; l++) {
            float sx = redf[l][0].x + redf[l][1].x + redf[l][2].x + redf[l][3].x;
            float sy = redf[l][0].y + redf[l][1].y + redf[l][2].y + redf[l][3].y;
            int Hl = 512 >> l;
            float cnt = (float)N * (float)Hl * (float)Hl;
            float ssim_m = sx / cnt;
            float mcs_m  = sy / cnt;
            if (l < 4) r *= powf(mcs_m, wts[l]);
            else       r *= powf(ssim_m, wts[4]);
        }
        out[0] = r;
    }
}

extern "C" void kernel_launch(void* const* d_in, const int* in_sizes, int n_in,
                              void* d_out, int out_size, void* d_ws, size_t ws_size,
                              hipStream_t stream) {
    const float* img1 = (const float*)d_in[0];
    const float* img2 = (const float*)d_in[1];
    float* out = (float*)d_out;
    const int HW0 = 512 * 512;
    const int N = in_sizes[0] / HW0;  // 32

    float* base = (float*)d_ws;
    size_t cur = 0;
    float* l1a = base + cur; cur += (size_t)N * 256 * 256;
    float* l1b = base + cur; cur += (size_t)N * 256 * 256;
    float* l2a = base + cur; cur += (size_t)N * 128 * 128;
    float* l2b = base + cur; cur += (size_t)N * 128 * 128;
    float* l3a = base + cur; cur += (size_t)N * 64 * 64;
    float* l3b = base + cur; cur += (size_t)N * 64 * 64;
    float* l4a = base + cur; cur += (size_t)N * 32 * 32;
    float* l4b = base + cur; cur += (size_t)N * 32 * 32;
    float2* res0 = (float2*)(base + cur); cur += (size_t)N * 512;
    float2* res1 = (float2*)(base + cur); cur += (size_t)N * 128;
    float2* res2 = (float2*)(base + cur); cur += (size_t)N * 32;
    float2* res3 = (float2*)(base + cur); cur += (size_t)N * 8;
    float2* res4 = (float2*)(base + cur); cur += (size_t)N * 2;

    GaussW gw;
    {
        double g[11], sum = 0.0;
        for (int i = 0; i < 11; i++) {
            double x = (double)(i - 5);
            g[i] = exp(-(x * x) / (2.0 * 1.5 * 1.5));
            sum += g[i];
        }
        for (int i = 0; i < 11; i++) gw.w[i] = (float)(g[i] / sum);
    }

    d1_kernel<<<dim3(320, N), 256, 0, stream>>>(
        img1, img2, l1a, l1b, l2a, l2b, l3a, l3b, l4a, l4b, res0, gw);
    d2_kernel<<<dim3(85, N), 256, 0, stream>>>(
        l1a, l1b, l2a, l2b, l3a, l3b, l4a, l4b, res1, res2, res3, res4, gw);
    finalize_kernel<<<1, 256, 0, stream>>>(res0, res1, res2, res3, res4, out, N);
}

// Round 14
// 151.574 us; speedup vs baseline: 1.0428x; 1.0428x over previous
//
#include <hip/hip_runtime.h>
#include <math.h>

// MS-SSIM, 5 levels, fp32, N=32 of 512x512.
// R14: R12 base (R13 LDS swizzle reverted — conflicts were hidden, swizzle
//      cost real time). New: XCD-aware block remap in d1:
//      swz = (lb&7)*(total/8) + (lb>>3) -> each XCD processes a contiguous
//      tile range, so vertical-halo rows hit that XCD's L2 instead of
//      re-fetching from HBM (FETCH was 115MB vs 67MB ideal).
//      Carried: 4-channel sum/diff blur, v4f LDS, fast rcp, packed epilogue,
//      folded constants, interior fast path, lb(256,7), d1 = pyramid + L0,
//      d2 = L1-4, tiny finalize, unique result slots.

typedef float v2f __attribute__((ext_vector_type(2)));
typedef float v4f __attribute__((ext_vector_type(4)));

#define TILE 32
#define HALO 5
#define SROWS 42   // TILE + 2*HALO
#define SMEM_FLOATS 5384  // hb v4f[SROWS*TILE] = 5376f | red 8f

struct GaussW { float w[11]; };

#define C1X2 (2.0f * 0.01f * 0.01f)
#define C2X2 (2.0f * 0.03f * 0.03f)

__device__ __forceinline__ void ssim_tile(
        const float* __restrict__ p1, const float* __restrict__ p2,
        int W, int tile_x, int tile_y, const GaussW& gw,
        float2* __restrict__ resslot, float* smem, int tid) {
    v4f* hb = (v4f*)smem;                 // [SROWS*TILE] {bs,bd,bs2,bd2}
    float* red = smem + 4 * SROWS * TILE; // [8]

    const bool xfast = (tile_x >= 8) && (tile_x + TILE + 8 <= W);
    const bool allfast = xfast && (tile_y > 0) && (tile_y + TILE < W);

    // ---- stage A: horizontal blur of (s,d) and (s^2,d^2) ----
    for (int it = tid; it < SROWS * 8; it += 256) {
        int r = it >> 3, c4 = it & 7;
        int gy = tile_y + r - HALO;
        int gx0 = tile_x + (c4 << 2) - 8;
        const float* row1 = p1 + (size_t)gy * W;
        const float* row2 = p2 + (size_t)gy * W;
        float a1[20], a2[20];
        if (allfast) {
#pragma unroll
            for (int q = 0; q < 5; q++) {
                float4 v1 = *(const float4*)(row1 + gx0 + q * 4);
                float4 v2v = *(const float4*)(row2 + gx0 + q * 4);
                a1[q*4+0] = v1.x;  a1[q*4+1] = v1.y;  a1[q*4+2] = v1.z;  a1[q*4+3] = v1.w;
                a2[q*4+0] = v2v.x; a2[q*4+1] = v2v.y; a2[q*4+2] = v2v.z; a2[q*4+3] = v2v.w;
            }
        } else {
            bool rowok = (gy >= 0) && (gy < W);
#pragma unroll
            for (int i = 0; i < 20; i++) { a1[i] = 0.f; a2[i] = 0.f; }
            if (xfast) {
                if (rowok) {
#pragma unroll
                    for (int q = 0; q < 5; q++) {
                        float4 v1 = *(const float4*)(row1 + gx0 + q * 4);
                        float4 v2v = *(const float4*)(row2 + gx0 + q * 4);
                        a1[q*4+0] = v1.x;  a1[q*4+1] = v1.y;  a1[q*4+2] = v1.z;  a1[q*4+3] = v1.w;
                        a2[q*4+0] = v2v.x; a2[q*4+1] = v2v.y; a2[q*4+2] = v2v.z; a2[q*4+3] = v2v.w;
                    }
                }
            } else {
#pragma unroll
                for (int q = 0; q < 5; q++) {
                    int g = gx0 + q * 4;
                    if (rowok && g >= 0 && g + 4 <= W) {
                        float4 v1 = *(const float4*)(row1 + g);
                        float4 v2v = *(const float4*)(row2 + g);
                        a1[q*4+0] = v1.x;  a1[q*4+1] = v1.y;  a1[q*4+2] = v1.z;  a1[q*4+3] = v1.w;
                        a2[q*4+0] = v2v.x; a2[q*4+1] = v2v.y; a2[q*4+2] = v2v.z; a2[q*4+3] = v2v.w;
                    }
                }
            }
        }
        v2f SD[14], SQ[14];
#pragma unroll
        for (int i = 0; i < 14; i++) {
            float x = a1[i + 3], y = a2[i + 3];
            v2f sd = {x + y, x - y};
            SD[i] = sd;
            SQ[i] = sd * sd;
        }
        v2f hsd[4] = {(v2f)(0.f), (v2f)(0.f), (v2f)(0.f), (v2f)(0.f)};
        v2f hsq[4] = {(v2f)(0.f), (v2f)(0.f), (v2f)(0.f), (v2f)(0.f)};
#pragma unroll
        for (int k = 0; k < 11; k++) {
            float wk = gw.w[k];
#pragma unroll
            for (int j = 0; j < 4; j++) {
                hsd[j] += wk * SD[j + k];
                hsq[j] += wk * SQ[j + k];
            }
        }
        int ob = r * TILE + (c4 << 2);
#pragma unroll
        for (int j = 0; j < 4; j++) {
            hb[ob + j] = (v4f){hsd[j].x, hsd[j].y, hsq[j].x, hsq[j].y};
        }
    }
    __syncthreads();

    // ---- stage B: vertical blur (b128 reads) + packed ssim/mcs ----
    float ssim_v = 0.f, mcs_v = 0.f;
    {
        int tx = tid & 31, y0 = (tid >> 5) * 4;
        v4f m[4];
        {
            v4f v[14];
#pragma unroll
            for (int r = 0; r < 14; r++) v[r] = hb[(y0 + r) * TILE + tx];
#pragma unroll
            for (int j = 0; j < 4; j++) {
                v4f s = (v4f)(0.f);
#pragma unroll
                for (int k = 0; k < 11; k++) s += gw.w[k] * v[j + k];
                m[j] = s;
            }
        }
#pragma unroll
        for (int p = 0; p < 2; p++) {
            v2f bs  = {m[2*p].x, m[2*p+1].x};
            v2f bd  = {m[2*p].y, m[2*p+1].y};
            v2f bs2 = {m[2*p].z, m[2*p+1].z};
            v2f bd2 = {m[2*p].w, m[2*p+1].w};
            v2f qp = bs * bs, qm = bd * bd;
            v2f u = bs2 - qp, v = bd2 - qm;
            v2f mden = (u + v) + (v2f)(C2X2);
            v2f sden = (qp + qm) + (v2f)(C1X2);
            v2f rm = {__builtin_amdgcn_rcpf(mden.x), __builtin_amdgcn_rcpf(mden.y)};
            v2f rs = {__builtin_amdgcn_rcpf(sden.x), __builtin_amdgcn_rcpf(sden.y)};
            v2f mcs  = ((u - v) + (v2f)(C2X2)) * rm;
            v2f ssim = ((qp - qm) + (v2f)(C1X2)) * rs * mcs;
            ssim_v += ssim.x + ssim.y;
            mcs_v  += mcs.x + mcs.y;
        }
    }

    // ---- block reduction + unique-slot store ----
#pragma unroll
    for (int off = 32; off > 0; off >>= 1) {
        ssim_v += __shfl_down(ssim_v, off);
        mcs_v  += __shfl_down(mcs_v, off);
    }
    int wave = tid >> 6, lane = tid & 63;
    if (lane == 0) { red[wave] = ssim_v; red[4 + wave] = mcs_v; }
    __syncthreads();
    if (tid == 0) {
        float S = red[0] + red[1] + red[2] + red[3];
        float M = red[4] + red[5] + red[6] + red[7];
        *resslot = make_float2(S, M);
    }
}

// pyramid region: 64x64 of L0 -> L1 32x32 (store), L2 16x16, L3 8x8, L4 4x4
__device__ __forceinline__ void pyramid_region(
        const float* __restrict__ in1, const float* __restrict__ in2,
        int n, int reg,
        float* __restrict__ l1a, float* __restrict__ l1b,
        float* __restrict__ l2a, float* __restrict__ l2b,
        float* __restrict__ l3a, float* __restrict__ l3b,
        float* __restrict__ l4a, float* __restrict__ l4b,
        float* smem, int tid) {
    float* b1 = smem;          // 32*32 (L1)
    float* b2 = smem + 1024;
    float* c1 = smem + 2048;   // 16*16 (L2)
    float* c2 = smem + 2304;
    float* d1 = smem + 2560;   // 8*8 (L3)
    float* d2 = smem + 2624;
    const int rx = reg & 7, ry = reg >> 3;
    const float* p1 = in1 + (size_t)n * 512 * 512;
    const float* p2 = in2 + (size_t)n * 512 * 512;

    // L1 (store)
    for (int i = tid; i < 32 * 16; i += 256) {
        int oy = i >> 4, oxp = i & 15;
        int gy = ry * 64 + 2 * oy, gx = rx * 64 + 4 * oxp;
        float4 r10 = *(const float4*)(p1 + (size_t)gy * 512 + gx);
        float4 r11 = *(const float4*)(p1 + (size_t)(gy + 1) * 512 + gx);
        float4 r20 = *(const float4*)(p2 + (size_t)gy * 512 + gx);
        float4 r21 = *(const float4*)(p2 + (size_t)(gy + 1) * 512 + gx);
        float2 o1 = make_float2(0.25f * (r10.x + r10.y + r11.x + r11.y),
                                0.25f * (r10.z + r10.w + r11.z + r11.w));
        float2 o2 = make_float2(0.25f * (r20.x + r20.y + r21.x + r21.y),
                                0.25f * (r20.z + r20.w + r21.z + r21.w));
        *(float2*)&b1[oy * 32 + 2 * oxp] = o1;
        *(float2*)&b2[oy * 32 + 2 * oxp] = o2;
        size_t o = (size_t)n * 256 * 256 + (size_t)(ry * 32 + oy) * 256 + rx * 32 + 2 * oxp;
        *(float2*)&l1a[o] = o1;
        *(float2*)&l1b[o] = o2;
    }
    __syncthreads();
    // L2 (store)
    if (tid < 16 * 8) {
        int oy = tid >> 3, oxp = tid & 7;
        float4 r10 = *(const float4*)&b1[(2 * oy) * 32 + 4 * oxp];
        float4 r11 = *(const float4*)&b1[(2 * oy + 1) * 32 + 4 * oxp];
        float4 r20 = *(const float4*)&b2[(2 * oy) * 32 + 4 * oxp];
        float4 r21 = *(const float4*)&b2[(2 * oy + 1) * 32 + 4 * oxp];
        float2 o1 = make_float2(0.25f * (r10.x + r10.y + r11.x + r11.y),
                                0.25f * (r10.z + r10.w + r11.z + r11.w));
        float2 o2 = make_float2(0.25f * (r20.x + r20.y + r21.x + r21.y),
                                0.25f * (r20.z + r20.w + r21.z + r21.w));
        *(float2*)&c1[oy * 16 + 2 * oxp] = o1;
        *(float2*)&c2[oy * 16 + 2 * oxp] = o2;
        size_t o = (size_t)n * 128 * 128 + (size_t)(ry * 16 + oy) * 128 + rx * 16 + 2 * oxp;
        *(float2*)&l2a[o] = o1;
        *(float2*)&l2b[o] = o2;
    }
    __syncthreads();
    // L3 (store)
    if (tid < 8 * 4) {
        int oy = tid >> 2, oxp = tid & 3;
        float4 r10 = *(const float4*)&c1[(2 * oy) * 16 + 4 * oxp];
        float4 r11 = *(const float4*)&c1[(2 * oy + 1) * 16 + 4 * oxp];
        float4 r20 = *(const float4*)&c2[(2 * oy) * 16 + 4 * oxp];
        float4 r21 = *(const float4*)&c2[(2 * oy + 1) * 16 + 4 * oxp];
        float2 o1 = make_float2(0.25f * (r10.x + r10.y + r11.x + r11.y),
                                0.25f * (r10.z + r10.w + r11.z + r11.w));
        float2 o2 = make_float2(0.25f * (r20.x + r20.y + r21.x + r21.y),
                                0.25f * (r20.z + r20.w + r21.z + r21.w));
        *(float2*)&d1[oy * 8 + 2 * oxp] = o1;
        *(float2*)&d2[oy * 8 + 2 * oxp] = o2;
        size_t o = (size_t)n * 64 * 64 + (size_t)(ry * 8 + oy) * 64 + rx * 8 + 2 * oxp;
        *(float2*)&l3a[o] = o1;
        *(float2*)&l3b[o] = o2;
    }
    __syncthreads();
    // L4 (store)
    if (tid < 4 * 2) {
        int oy = tid >> 1, oxp = tid & 1;
        float4 r10 = *(const float4*)&d1[(2 * oy) * 8 + 4 * oxp];
        float4 r11 = *(const float4*)&d1[(2 * oy + 1) * 8 + 4 * oxp];
        float4 r20 = *(const float4*)&d2[(2 * oy) * 8 + 4 * oxp];
        float4 r21 = *(const float4*)&d2[(2 * oy + 1) * 8 + 4 * oxp];
        float2 o1 = make_float2(0.25f * (r10.x + r10.y + r11.x + r11.y),
                                0.25f * (r10.z + r10.w + r11.z + r11.w));
        float2 o2 = make_float2(0.25f * (r20.x + r20.y + r21.x + r21.y),
                                0.25f * (r20.z + r20.w + r21.z + r21.w));
        size_t o = (size_t)n * 32 * 32 + (size_t)(ry * 4 + oy) * 32 + rx * 4 + 2 * oxp;
        *(float2*)&l4a[o] = o1;
        *(float2*)&l4b[o] = o2;
    }
}

// D1: XCD-aware remap, then t<64 pyramid region; t in [64,320) L0 tile.
__global__ __launch_bounds__(256, 7) void d1_kernel(
        const float* __restrict__ i0a, const float* __restrict__ i0b,
        float* __restrict__ l1a, float* __restrict__ l1b,
        float* __restrict__ l2a, float* __restrict__ l2b,
        float* __restrict__ l3a, float* __restrict__ l3b,
        float* __restrict__ l4a, float* __restrict__ l4b,
        float2* __restrict__ res0, int total, GaussW gw) {
    __shared__ float smem[SMEM_FLOATS];
    const int tid = threadIdx.x;
    // XCD-aware remap: consecutive lb round-robin across 8 XCDs; give each
    // XCD a contiguous tile range so halo rows hit its L2.
    int lb = blockIdx.x + gridDim.x * blockIdx.y;
    int swz = ((total & 7) == 0) ? ((lb & 7) * (total >> 3) + (lb >> 3)) : lb;
    const int t = swz % 320;
    const int n = swz / 320;
    if (t < 64) {
        pyramid_region(i0a, i0b, n, t, l1a, l1b, l2a, l2b, l3a, l3b, l4a, l4b,
                       smem, tid);
    } else {
        int idx = t - 64;
        const float* p1 = i0a + (size_t)n * 512 * 512;
        const float* p2 = i0b + (size_t)n * 512 * 512;
        ssim_tile(p1, p2, 512, (idx & 15) << 5, (idx >> 4) << 5,
                  gw, &res0[n * 256 + idx], smem, tid);
    }
}

// D2: t<64 L1 tile; [64,80) L2; [80,84) L3; 84 L4.
__global__ __launch_bounds__(256, 7) void d2_kernel(
        const float* __restrict__ l1a, const float* __restrict__ l1b,
        const float* __restrict__ l2a, const float* __restrict__ l2b,
        const float* __restrict__ l3a, const float* __restrict__ l3b,
        const float* __restrict__ l4a, const float* __restrict__ l4b,
        float2* __restrict__ res1, float2* __restrict__ res2,
        float2* __restrict__ res3, float2* __restrict__ res4, GaussW gw) {
    __shared__ float smem[SMEM_FLOATS];
    const int tid = threadIdx.x;
    const int t = blockIdx.x;
    const int n = blockIdx.y;
    const float* b1;
    const float* b2;
    int W, tx, ty;
    float2* slot;
    if (t < 64)      { W = 256; b1 = l1a; b2 = l1b; tx = (t & 7) << 5; ty = (t >> 3) << 5; slot = &res1[n * 64 + t]; }
    else if (t < 80) { int i = t - 64; W = 128; b1 = l2a; b2 = l2b; tx = (i & 3) << 5; ty = (i >> 2) << 5; slot = &res2[n * 16 + i]; }
    else if (t < 84) { int i = t - 80; W = 64; b1 = l3a; b2 = l3b; tx = (i & 1) << 5; ty = (i >> 1) << 5; slot = &res3[n * 4 + i]; }
    else             { W = 32; b1 = l4a; b2 = l4b; tx = 0; ty = 0; slot = &res4[n]; }
    ssim_tile(b1 + (size_t)n * W * W, b2 + (size_t)n * W * W, W,
              tx, ty, gw, slot, smem, tid);
}

__global__ void finalize_kernel(const float2* __restrict__ res0,
                                const float2* __restrict__ res1,
                                const float2* __restrict__ res2,
                                const float2* __restrict__ res3,
                                const float2* __restrict__ res4,
                                float* __restrict__ out, int N) {
    __shared__ float2 redf[5][4];
    const int tid = threadIdx.x;
    const float2* rr[5] = {res0, res1, res2, res3, res4};
    const int cnts[5] = {N * 256, N * 64, N * 16, N * 4, N};
#pragma unroll
    for (int l = 0; l < 5; l++) {
        float sx = 0.f, sy = 0.f;
        for (int i = tid; i < cnts[l]; i += 256) {
            float2 v = rr[l][i];
            sx += v.x;
            sy += v.y;
        }
#pragma unroll
        for (int off = 32; off > 0; off >>= 1) {
            sx += __shfl_down(sx, off);
            sy += __shfl_down(sy, off);
        }
        if ((tid & 63) == 0) redf[l][tid >> 6] = make_float2(sx, sy);
    }
    __syncthreads();
    if (tid == 0) {
        const float wts[5] = {0.0448f, 0.2856f, 0.3001f, 0.2363f, 0.1333f};
        float r = 1.f;
#pragma unroll
        for (int l = 0; l < 5; l++) {
            float sx = redf[l][0].x + redf[l][1].x + redf[l][2].x + redf[l][3].x;
            float sy = redf[l][0].y + redf[l][1].y + redf[l][2].y + redf[l][3].y;
            int Hl = 512 >> l;
            float cnt = (float)N * (float)Hl * (float)Hl;
            float ssim_m = sx / cnt;
            float mcs_m  = sy / cnt;
            if (l < 4) r *= powf(mcs_m, wts[l]);
            else       r *= powf(ssim_m, wts[4]);
        }
        out[0] = r;
    }
}

extern "C" void kernel_launch(void* const* d_in, const int* in_sizes, int n_in,
                              void* d_out, int out_size, void* d_ws, size_t ws_size,
                              hipStream_t stream) {
    const float* img1 = (const float*)d_in[0];
    const float* img2 = (const float*)d_in[1];
    float* out = (float*)d_out;
    const int HW0 = 512 * 512;
    const int N = in_sizes[0] / HW0;  // 32

    float* base = (float*)d_ws;
    size_t cur = 0;
    float* l1a = base + cur; cur += (size_t)N * 256 * 256;
    float* l1b = base + cur; cur += (size_t)N * 256 * 256;
    float* l2a = base + cur; cur += (size_t)N * 128 * 128;
    float* l2b = base + cur; cur += (size_t)N * 128 * 128;
    float* l3a = base + cur; cur += (size_t)N * 64 * 64;
    float* l3b = base + cur; cur += (size_t)N * 64 * 64;
    float* l4a = base + cur; cur += (size_t)N * 32 * 32;
    float* l4b = base + cur; cur += (size_t)N * 32 * 32;
    float2* res0 = (float2*)(base + cur); cur += (size_t)N * 512;
    float2* res1 = (float2*)(base + cur); cur += (size_t)N * 128;
    float2* res2 = (float2*)(base + cur); cur += (size_t)N * 32;
    float2* res3 = (float2*)(base + cur); cur += (size_t)N * 8;
    float2* res4 = (float2*)(base + cur); cur += (size_t)N * 2;

    GaussW gw;
    {
        double g[11], sum = 0.0;
        for (int i = 0; i < 11; i++) {
            double x = (double)(i - 5);
            g[i] = exp(-(x * x) / (2.0 * 1.5 * 1.5));
            sum += g[i];
        }
        for (int i = 0; i < 11; i++) gw.w[i] = (float)(g[i] / sum);
    }

    d1_kernel<<<dim3(320, N), 256, 0, stream>>>(
        img1, img2, l1a, l1b, l2a, l2b, l3a, l3b, l4a, l4b, res0, 320 * N, gw);
    d2_kernel<<<dim3(85, N), 256, 0, stream>>>(
        l1a, l1b, l2a, l2b, l3a, l3b, l4a, l4b, res1, res2, res3, res4, gw);
    finalize_kernel<<<1, 256, 0, stream>>>(res0, res1, res2, res3, res4, out, N);
}